// Round 3
// baseline (6246.918 us; speedup 1.0000x reference)
//
#include <hip/hip_runtime.h>
#include <hip/hip_bf16.h>
#include <math.h>

typedef unsigned short u16;
typedef __attribute__((ext_vector_type(4))) float f32x4;
typedef __attribute__((ext_vector_type(8))) short s16x8;

#define BB  512
#define TT  120
#define LAT 292
#define HH1 701
#define HH3 901
#define H1P 704
#define H3P 960
#define CH  35

// ws layout (bytes, all 256-aligned)
static const size_t O_X    = 0;                     // 512*292*4
static const size_t O_XP1  = 598016;                // 512*2112*4
static const size_t O_H1F  = 4923392;               // 2*512*704*4
static const size_t O_H2F  = 7806976;               // 2*512*704*4
static const size_t O_H3F  = 10690560;              // 2*512*960*4
static const size_t O_H1B  = 14622720;              // 2*512*704*2
static const size_t O_H2B  = 16064512;              // 2*512*704*2
static const size_t O_H3B  = 17506304;              // 2*512*960*2
static const size_t O_WHT1 = 19472384;              // 2112*704*2
static const size_t O_WIT2 = 22446080;              // 2112*704*2
static const size_t O_WHT2 = 25419776;              // 2112*704*2
static const size_t O_WIT3 = 28393472;              // 2816*704*2
static const size_t O_WHT3 = 32358400;              // 2816*960*2
static const size_t O_WOT  = 37765120;              // 64*960*2
static const size_t ZERO_BYTES = 14548992;          // O_H1F..O_H3B end

static __device__ __forceinline__ u16 f2b(float f){
  union { float f; unsigned int i; } v; v.f = f;
  unsigned int x = v.i;
  return (u16)((x + 0x7FFFu + ((x >> 16) & 1u)) >> 16);
}

// ---------------- prologue: x = selu(z @ W1 + b1) ----------------
__launch_bounds__(256)
__global__ void k_selu(const float* __restrict__ z, const float* __restrict__ W1,
                       const float* __restrict__ b1, float* __restrict__ x)
{
  int idx = blockIdx.x * 256 + threadIdx.x;
  if (idx >= BB * LAT) return;
  int b = idx / LAT, i = idx - b * LAT;
  float acc = b1[i];
  const float* zr = z + (size_t)b * LAT;
  for (int k = 0; k < LAT; ++k)
    acc += zr[k] * W1[k * LAT + i];
  const float alpha = 1.6732632423543772f, scale = 1.0507009873554805f;
  x[idx] = scale * (acc > 0.f ? acc : alpha * (expf(acc) - 1.f));
}

// ---------------- prologue: xp1 = x @ Wi1 + bi1 (f32, [512][2112]) ----------------
__launch_bounds__(256)
__global__ void k_xp1(const float* __restrict__ x, const float* __restrict__ Wi1,
                      const float* __restrict__ bi1, float* __restrict__ xp1)
{
  int nb = blockIdx.x % 9, bb = blockIdx.x / 9;
  int n = nb * 256 + threadIdx.x;
  int b0 = bb * 8;
  if (n >= 2112) return;
  if (n >= 2103) { for (int r = 0; r < 8; ++r) xp1[(size_t)(b0 + r) * 2112 + n] = 0.f; return; }
  float bias = bi1[n];
  float acc[8];
  for (int r = 0; r < 8; ++r) acc[r] = bias;
  for (int k = 0; k < LAT; ++k) {
    float w = Wi1[(size_t)k * 2103 + n];
    #pragma unroll
    for (int r = 0; r < 8; ++r) acc[r] += x[(size_t)(b0 + r) * LAT + k] * w;
  }
  for (int r = 0; r < 8; ++r) xp1[(size_t)(b0 + r) * 2112 + n] = acc[r];
}

// ---------------- prologue: WT[n][k] = bf16(W[k][n]), zero-padded ----------------
__launch_bounds__(256)
__global__ void k_transpose(const float* __restrict__ W, u16* __restrict__ WT,
                            int K, int N, int Kpad, int RowsPad)
{
  int tilesN = RowsPad / 64;
  int tk = blockIdx.x / tilesN, tn = blockIdx.x % tilesN;
  int k0 = tk * 64, n0 = tn * 64;
  __shared__ u16 lds[64][72];
  int tid = threadIdx.x;
  int nl = tid & 63, q = tid >> 6;
  for (int i = 0; i < 16; ++i) {
    int kl = q * 16 + i;
    int k = k0 + kl, n = n0 + nl;
    lds[kl][nl] = (k < K && n < N) ? f2b(W[(size_t)k * N + n]) : (u16)0;
  }
  __syncthreads();
  for (int i = 0; i < 16; ++i) {
    int rl = q * 16 + i;
    WT[(size_t)(n0 + rl) * Kpad + k0 + nl] = lds[nl][rl];
  }
}

// ---------------- GRU matmul segment (HACC = acc index for h-gate, compile-time) ----------------
template<int HACC>
__device__ __forceinline__ void gru_mm_seg(
    const u16* __restrict__ Aseg, const u16* __restrict__ Wt,
    int As, int Wst, int Ks, int H, int r0, int j0,
    int row_s, int kc, int wr, int wc, int m16, int kg,
    u16 (*ldsA)[40], u16 (*ldsB)[64][40],
    f32x4 (&acc)[4][2][2])
{
  for (int ks = 0; ks < Ks; ++ks) {
    int k0 = ks * 32;
    *(int4*)(&ldsA[row_s][kc]) = *(const int4*)(&Aseg[(size_t)(r0 + row_s) * As + k0 + kc]);
    #pragma unroll
    for (int g = 0; g < 3; ++g)
      *(int4*)(&ldsB[g][row_s][kc]) = *(const int4*)(&Wt[(size_t)(g * H + j0 + row_s) * Wst + k0 + kc]);
    __syncthreads();
    s16x8 af[2], bfr[3][2];
    #pragma unroll
    for (int fm = 0; fm < 2; ++fm) af[fm] = *(const s16x8*)(&ldsA[wr * 32 + fm * 16 + m16][kg * 8]);
    #pragma unroll
    for (int g = 0; g < 3; ++g)
      #pragma unroll
      for (int fn = 0; fn < 2; ++fn)
        bfr[g][fn] = *(const s16x8*)(&ldsB[g][wc * 32 + fn * 16 + m16][kg * 8]);
    #pragma unroll
    for (int fm = 0; fm < 2; ++fm)
      #pragma unroll
      for (int fn = 0; fn < 2; ++fn) {
        acc[0][fm][fn]    = __builtin_amdgcn_mfma_f32_16x16x32_bf16(af[fm], bfr[0][fn], acc[0][fm][fn], 0, 0, 0);
        acc[1][fm][fn]    = __builtin_amdgcn_mfma_f32_16x16x32_bf16(af[fm], bfr[1][fn], acc[1][fm][fn], 0, 0, 0);
        acc[HACC][fm][fn] = __builtin_amdgcn_mfma_f32_16x16x32_bf16(af[fm], bfr[2][fn], acc[HACC][fm][fn], 0, 0, 0);
      }
    __syncthreads();
  }
}

// ---------------- wavefront step kernel ----------------
// bid [0,120): GRU3 (t=s-2)   [120,208): GRU2 (t=s-1)
// bid [208,296): GRU1 (t=s)   [296,304): out-proj+softmax (t=s-3)
__launch_bounds__(256)
__global__ void k_wave(int s,
    const u16* __restrict__ WhT1, const u16* __restrict__ WiT2, const u16* __restrict__ WhT2,
    const u16* __restrict__ WiT3, const u16* __restrict__ WhT3, const u16* __restrict__ WoT,
    const float* __restrict__ xp1,
    const float* __restrict__ gbh1,
    const float* __restrict__ gbi2, const float* __restrict__ gbh2,
    const float* __restrict__ gbi3, const float* __restrict__ gbh3,
    const float* __restrict__ bo,
    float* __restrict__ h1f, u16* __restrict__ h1b,
    float* __restrict__ h2f, u16* __restrict__ h2b,
    float* __restrict__ h3f, u16* __restrict__ h3b,
    float* __restrict__ out)
{
  __shared__ __align__(16) char smraw[20480];
  u16 (*ldsA)[40]      = (u16 (*)[40])smraw;
  u16 (*ldsB)[64][40]  = (u16 (*)[64][40])(smraw + 5120);
  float (*ldsL)[67]    = (float (*)[67])smraw;

  const int tid  = threadIdx.x;
  const int lane = tid & 63;
  const int wave = tid >> 6;
  const int wr = wave >> 1, wc = wave & 1;
  const int m16 = lane & 15, kg = lane >> 4;
  const int row_s = tid >> 2, kc = (tid & 3) * 8;

  int bid = blockIdx.x;
  int layer, lb;
  if (bid < 120)      { layer = 3; lb = bid; }
  else if (bid < 208) { layer = 2; lb = bid - 120; }
  else if (bid < 296) { layer = 1; lb = bid - 208; }
  else                { layer = 4; lb = bid - 296; }

  const int t = s - (layer - 1);
  if (t < 0 || t >= TT) return;
  const int cur = s & 1, prv = cur ^ 1;

  if (layer == 4) {
    // ---- output projection + softmax over charset for t = s-3 ----
    const int r0 = lb * 64;
    const u16* A = h3b + (size_t)prv * BB * H3P;
    f32x4 acc[2][2];
    f32x4 z4 = {0.f, 0.f, 0.f, 0.f};
    for (int a = 0; a < 2; ++a) for (int b = 0; b < 2; ++b) acc[a][b] = z4;
    for (int ks = 0; ks < H3P / 32; ++ks) {
      int k0 = ks * 32;
      *(int4*)(&ldsA[row_s][kc])    = *(const int4*)(&A[(size_t)(r0 + row_s) * H3P + k0 + kc]);
      *(int4*)(&ldsB[0][row_s][kc]) = *(const int4*)(&WoT[(size_t)row_s * H3P + k0 + kc]);
      __syncthreads();
      s16x8 af[2], bfr[2];
      #pragma unroll
      for (int fm = 0; fm < 2; ++fm) af[fm] = *(const s16x8*)(&ldsA[wr * 32 + fm * 16 + m16][kg * 8]);
      #pragma unroll
      for (int fn = 0; fn < 2; ++fn) bfr[fn] = *(const s16x8*)(&ldsB[0][wc * 32 + fn * 16 + m16][kg * 8]);
      #pragma unroll
      for (int fm = 0; fm < 2; ++fm)
        #pragma unroll
        for (int fn = 0; fn < 2; ++fn)
          acc[fm][fn] = __builtin_amdgcn_mfma_f32_16x16x32_bf16(af[fm], bfr[fn], acc[fm][fn], 0, 0, 0);
      __syncthreads();
    }
    // logits -> LDS
    #pragma unroll
    for (int fn = 0; fn < 2; ++fn) {
      int c = wc * 32 + fn * 16 + m16;
      float bov = (c < CH) ? bo[c] : 0.f;
      #pragma unroll
      for (int fm = 0; fm < 2; ++fm)
        #pragma unroll
        for (int ii = 0; ii < 4; ++ii)
          ldsL[wr * 32 + fm * 16 + kg * 4 + ii][c] = acc[fm][fn][ii] + bov;
    }
    __syncthreads();
    if (tid < 64) {
      int b = r0 + tid;
      float mx = -1e30f;
      for (int c = 0; c < CH; ++c) mx = fmaxf(mx, ldsL[tid][c]);
      float sum = 0.f;
      for (int c = 0; c < CH; ++c) sum += expf(ldsL[tid][c] - mx);
      float inv = 1.f / sum;
      size_t ob = ((size_t)b * TT + t) * CH;
      for (int c = 0; c < CH; ++c) out[ob + c] = expf(ldsL[tid][c] - mx) * inv;
    }
    return;
  }

  // ---- GRU layers ----
  int H, HP, NJ;
  const u16 *Wx = nullptr, *Wh = nullptr, *Ax = nullptr, *Ah = nullptr;
  const float *bi = nullptr, *bh = nullptr;
  int AxS = 0, AhS = 0, KxSteps = 0, KhSteps = 0, WxS = 0, WhS = 0;
  float *hfP, *hfC; u16 *hbC;
  if (layer == 1) {
    H = HH1; HP = H1P; NJ = 11;
    Ah = h1b + (size_t)prv * BB * H1P; AhS = H1P; KhSteps = H1P / 32; Wh = WhT1; WhS = H1P;
    bh = gbh1;
    hfP = h1f + (size_t)prv * BB * H1P; hfC = h1f + (size_t)cur * BB * H1P; hbC = h1b + (size_t)cur * BB * H1P;
  } else if (layer == 2) {
    H = HH1; HP = H1P; NJ = 11;
    Ax = h1b + (size_t)prv * BB * H1P; AxS = H1P; KxSteps = H1P / 32; Wx = WiT2; WxS = H1P;
    Ah = h2b + (size_t)prv * BB * H1P; AhS = H1P; KhSteps = H1P / 32; Wh = WhT2; WhS = H1P;
    bi = gbi2; bh = gbh2;
    hfP = h2f + (size_t)prv * BB * H1P; hfC = h2f + (size_t)cur * BB * H1P; hbC = h2b + (size_t)cur * BB * H1P;
  } else {
    H = HH3; HP = H3P; NJ = 15;
    Ax = h2b + (size_t)prv * BB * H1P; AxS = H1P; KxSteps = H1P / 32; Wx = WiT3; WxS = H1P;
    Ah = h3b + (size_t)prv * BB * H3P; AhS = H3P; KhSteps = H3P / 32; Wh = WhT3; WhS = H3P;
    bi = gbi3; bh = gbh3;
    hfP = h3f + (size_t)prv * BB * H3P; hfC = h3f + (size_t)cur * BB * H3P; hbC = h3b + (size_t)cur * BB * H3P;
  }
  const int mi = lb / NJ, ni = lb % NJ;
  const int r0 = mi * 64, j0 = ni * 64;

  // acc groups: 0 = z (x+h summed), 1 = r (summed), 2 = xh, 3 = rh
  f32x4 acc[4][2][2];
  {
    f32x4 z4 = {0.f, 0.f, 0.f, 0.f};
    for (int g = 0; g < 4; ++g) for (int a = 0; a < 2; ++a) for (int b = 0; b < 2; ++b) acc[g][a][b] = z4;
  }

  if (layer != 1)
    gru_mm_seg<2>(Ax, Wx, AxS, WxS, KxSteps, H, r0, j0, row_s, kc, wr, wc, m16, kg, ldsA, ldsB, acc);
  gru_mm_seg<3>(Ah, Wh, AhS, WhS, KhSteps, H, r0, j0, row_s, kc, wr, wc, m16, kg, ldsA, ldsB, acc);

  // ---- gate epilogue ----
  #pragma unroll
  for (int fn = 0; fn < 2; ++fn) {
    int j = j0 + wc * 32 + fn * 16 + m16;
    if (j >= H) continue;
    float bhz = bh[j], bhr = bh[H + j], bhh = bh[2 * H + j];
    float biz = 0.f, bir = 0.f, bih = 0.f;
    if (layer != 1) { biz = bi[j]; bir = bi[H + j]; bih = bi[2 * H + j]; }
    #pragma unroll
    for (int fm = 0; fm < 2; ++fm) {
      #pragma unroll
      for (int ii = 0; ii < 4; ++ii) {
        int row = r0 + wr * 32 + fm * 16 + kg * 4 + ii;
        float az  = acc[0][fm][fn][ii];
        float ar  = acc[1][fm][fn][ii];
        float axh = acc[2][fm][fn][ii];
        float arh = acc[3][fm][fn][ii];
        float pz, pr, xh_, rh_;
        if (layer == 1) {
          const float* xr_ = xp1 + (size_t)row * 2112;
          pz  = xr_[j] + az + bhz;
          pr  = xr_[HH1 + j] + ar + bhr;
          xh_ = xr_[2 * HH1 + j];
          rh_ = arh + bhh;
        } else {
          pz  = az + biz + bhz;
          pr  = ar + bir + bhr;
          xh_ = axh + bih;
          rh_ = arh + bhh;
        }
        float zg = 1.f / (1.f + expf(-pz));
        float rg = 1.f / (1.f + expf(-pr));
        float hh = tanhf(xh_ + rg * rh_);
        float hp = hfP[(size_t)row * HP + j];
        float hn = zg * hp + (1.f - zg) * hh;
        hfC[(size_t)row * HP + j] = hn;
        hbC[(size_t)row * HP + j] = f2b(hn);
      }
    }
  }
}

// ---------------- host ----------------
extern "C" void kernel_launch(void* const* d_in, const int* in_sizes, int n_in,
                              void* d_out, int out_size, void* d_ws, size_t ws_size,
                              hipStream_t stream)
{
  const float* z    = (const float*)d_in[0];
  const float* W1   = (const float*)d_in[1];
  const float* b1   = (const float*)d_in[2];
  const float* gWi1 = (const float*)d_in[3];
  const float* gWh1 = (const float*)d_in[4];
  const float* gbi1 = (const float*)d_in[5];
  const float* gbh1 = (const float*)d_in[6];
  const float* gWi2 = (const float*)d_in[7];
  const float* gWh2 = (const float*)d_in[8];
  const float* gbi2 = (const float*)d_in[9];
  const float* gbh2 = (const float*)d_in[10];
  const float* gWi3 = (const float*)d_in[11];
  const float* gWh3 = (const float*)d_in[12];
  const float* gbi3 = (const float*)d_in[13];
  const float* gbh3 = (const float*)d_in[14];
  const float* Wo   = (const float*)d_in[15];
  const float* bo   = (const float*)d_in[16];

  char* ws = (char*)d_ws;
  float* x_f  = (float*)(ws + O_X);
  float* xp1  = (float*)(ws + O_XP1);
  float* h1f  = (float*)(ws + O_H1F);
  float* h2f  = (float*)(ws + O_H2F);
  float* h3f  = (float*)(ws + O_H3F);
  u16*   h1b  = (u16*)(ws + O_H1B);
  u16*   h2b  = (u16*)(ws + O_H2B);
  u16*   h3b  = (u16*)(ws + O_H3B);
  u16*   WhT1 = (u16*)(ws + O_WHT1);
  u16*   WiT2 = (u16*)(ws + O_WIT2);
  u16*   WhT2 = (u16*)(ws + O_WHT2);
  u16*   WiT3 = (u16*)(ws + O_WIT3);
  u16*   WhT3 = (u16*)(ws + O_WHT3);
  u16*   WoT  = (u16*)(ws + O_WOT);

  hipMemsetAsync(ws + O_H1F, 0, ZERO_BYTES, stream);

  k_selu<<<(BB * LAT + 255) / 256, 256, 0, stream>>>(z, W1, b1, x_f);
  k_xp1<<<9 * 64, 256, 0, stream>>>(x_f, gWi1, gbi1, xp1);

  k_transpose<<<11 * 33, 256, 0, stream>>>(gWh1, WhT1, 701, 2103, 704, 2112);
  k_transpose<<<11 * 33, 256, 0, stream>>>(gWi2, WiT2, 701, 2103, 704, 2112);
  k_transpose<<<11 * 33, 256, 0, stream>>>(gWh2, WhT2, 701, 2103, 704, 2112);
  k_transpose<<<11 * 44, 256, 0, stream>>>(gWi3, WiT3, 701, 2703, 704, 2816);
  k_transpose<<<15 * 44, 256, 0, stream>>>(gWh3, WhT3, 901, 2703, 960, 2816);
  k_transpose<<<15 * 1, 256, 0, stream>>>(Wo, WoT, 901, 35, 960, 64);

  for (int s = 0; s < TT + 3; ++s)
    k_wave<<<304, 256, 0, stream>>>(s, WhT1, WiT2, WhT2, WiT3, WhT3, WoT, xp1,
                                    gbh1, gbi2, gbh2, gbi3, gbh3, bo,
                                    h1f, h1b, h2f, h2b, h3f, h3b, (float*)d_out);
}

// Round 4
// 5436.645 us; speedup vs baseline: 1.1490x; 1.1490x over previous
//
#include <hip/hip_runtime.h>
#include <hip/hip_bf16.h>
#include <math.h>

typedef unsigned short u16;
typedef __attribute__((ext_vector_type(4))) float f32x4;
typedef __attribute__((ext_vector_type(8))) short s16x8;

#define BB  512
#define TT  120
#define LAT 292
#define HH1 701
#define HH3 901
#define H1P 704
#define H3P 960
#define CH  35
#define GRID 512

// ws layout (bytes, all 256-aligned)
static const size_t O_X    = 0;                     // 512*292*4
static const size_t O_XP1  = 598016;                // 512*2112*4
static const size_t O_H1F  = 4923392;               // 2*512*704*4
static const size_t O_H2F  = 7806976;               // 2*512*704*4
static const size_t O_H3F  = 10690560;              // 2*512*960*4
static const size_t O_H1B  = 14622720;              // 2*512*704*2
static const size_t O_H2B  = 16064512;              // 2*512*704*2
static const size_t O_H3B  = 17506304;              // 2*512*960*2
static const size_t O_WHT1 = 19472384;              // 2112*704*2
static const size_t O_WIT2 = 22446080;              // 2112*704*2
static const size_t O_WHT2 = 25419776;              // 2112*704*2
static const size_t O_WIT3 = 28393472;              // 2816*704*2
static const size_t O_WHT3 = 32358400;              // 2816*960*2
static const size_t O_WOT  = 37765120;              // 64*960*2
static const size_t O_TAB  = 37888000;              // 512*2
static const size_t ZERO_BYTES = 14548992;          // O_H1F..O_H3B end

static __device__ __forceinline__ u16 f2b(float f){
  union { float f; unsigned int i; } v; v.f = f;
  unsigned int x = v.i;
  return (u16)((x + 0x7FFFu + ((x >> 16) & 1u)) >> 16);
}

// ---------------- prologue: x = selu(z @ W1 + b1) ----------------
__launch_bounds__(256)
__global__ void k_selu(const float* __restrict__ z, const float* __restrict__ W1,
                       const float* __restrict__ b1, float* __restrict__ x)
{
  int idx = blockIdx.x * 256 + threadIdx.x;
  if (idx >= BB * LAT) return;
  int b = idx / LAT, i = idx - b * LAT;
  float acc = b1[i];
  const float* zr = z + (size_t)b * LAT;
  for (int k = 0; k < LAT; ++k)
    acc += zr[k] * W1[k * LAT + i];
  const float alpha = 1.6732632423543772f, scale = 1.0507009873554805f;
  x[idx] = scale * (acc > 0.f ? acc : alpha * (expf(acc) - 1.f));
}

// ---------------- prologue: xp1 = x @ Wi1 + bi1 (f32, [512][2112]) ----------------
__launch_bounds__(256)
__global__ void k_xp1(const float* __restrict__ x, const float* __restrict__ Wi1,
                      const float* __restrict__ bi1, float* __restrict__ xp1)
{
  int nb = blockIdx.x % 9, bb = blockIdx.x / 9;
  int n = nb * 256 + threadIdx.x;
  int b0 = bb * 8;
  if (n >= 2112) return;
  if (n >= 2103) { for (int r = 0; r < 8; ++r) xp1[(size_t)(b0 + r) * 2112 + n] = 0.f; return; }
  float bias = bi1[n];
  float acc[8];
  for (int r = 0; r < 8; ++r) acc[r] = bias;
  for (int k = 0; k < LAT; ++k) {
    float w = Wi1[(size_t)k * 2103 + n];
    #pragma unroll
    for (int r = 0; r < 8; ++r) acc[r] += x[(size_t)(b0 + r) * LAT + k] * w;
  }
  for (int r = 0; r < 8; ++r) xp1[(size_t)(b0 + r) * 2112 + n] = acc[r];
}

// ---------------- prologue: WT[n][k] = bf16(W[k][n]), zero-padded ----------------
__launch_bounds__(256)
__global__ void k_transpose(const float* __restrict__ W, u16* __restrict__ WT,
                            int K, int N, int Kpad, int RowsPad)
{
  int tilesN = RowsPad / 64;
  int tk = blockIdx.x / tilesN, tn = blockIdx.x % tilesN;
  int k0 = tk * 64, n0 = tn * 64;
  __shared__ u16 lds[64][72];
  int tid = threadIdx.x;
  int nl = tid & 63, q = tid >> 6;
  for (int i = 0; i < 16; ++i) {
    int kl = q * 16 + i;
    int k = k0 + kl, n = n0 + nl;
    lds[kl][nl] = (k < K && n < N) ? f2b(W[(size_t)k * N + n]) : (u16)0;
  }
  __syncthreads();
  for (int i = 0; i < 16; ++i) {
    int rl = q * 16 + i;
    WT[(size_t)(n0 + rl) * Kpad + k0 + nl] = lds[nl][rl];
  }
}

// ---------------- prologue: block->tile table, XCD-pinned ----------------
// blockIdx p lands on XCD p%8 (round-robin dispatch). All 8 row-tiles of a
// weight-column-group read the SAME weight slice -> pin the group to one XCD
// so its slice stays L2-resident across all 120 wavefront steps.
__global__ void k_maketab(u16* __restrict__ tab)
{
  if (threadIdx.x != 0 || blockIdx.x != 0) return;
  for (int i = 0; i < GRID; ++i) tab[i] = 0xFFFF;
  int load[8], cnt[8];
  for (int x = 0; x < 8; ++x) { load[x] = 0; cnt[x] = 0; }
  const int lay_order[3] = {2, 1, 0};     // descending K-step weight
  const int lay_nj[3]    = {11, 11, 15};
  const int lay_w[3]     = {22, 44, 52};
  for (int oi = 0; oi < 3; ++oi) {
    int L = lay_order[oi];
    for (int c = 0; c < lay_nj[L]; ++c) {
      int best = -1;
      for (int x = 0; x < 8; ++x)
        if (cnt[x] <= 56 && (best < 0 || load[x] < load[best])) best = x;
      load[best] += lay_w[L] * 8;
      for (int r = 0; r < 8; ++r) {
        int p = best + 8 * cnt[best]; cnt[best]++;
        tab[p] = (u16)((L << 12) | (r * lay_nj[L] + c));
      }
    }
  }
  for (int r = 0; r < 8; ++r) {
    int best = -1;
    for (int x = 0; x < 8; ++x)
      if (cnt[x] <= 63 && (best < 0 || load[x] < load[best])) best = x;
    load[best] += 30;
    int p = best + 8 * cnt[best]; cnt[best]++;
    tab[p] = (u16)((3 << 12) | r);
  }
}

// ---------------- wavefront step kernel ----------------
// tab[blockIdx.x] -> (L, lb):  L=0:GRU1(t=s) 1:GRU2(t=s-1) 2:GRU3(t=s-2) 3:OUT(t=s-3)
__launch_bounds__(256)
__global__ void k_wave(int s, const u16* __restrict__ tab,
    const u16* __restrict__ WhT1, const u16* __restrict__ WiT2, const u16* __restrict__ WhT2,
    const u16* __restrict__ WiT3, const u16* __restrict__ WhT3, const u16* __restrict__ WoT,
    const float* __restrict__ xp1,
    const float* __restrict__ gbh1,
    const float* __restrict__ gbi2, const float* __restrict__ gbh2,
    const float* __restrict__ gbi3, const float* __restrict__ gbh3,
    const float* __restrict__ bo,
    float* __restrict__ h1f, u16* __restrict__ h1b,
    float* __restrict__ h2f, u16* __restrict__ h2b,
    float* __restrict__ h3f, u16* __restrict__ h3b,
    float* __restrict__ out)
{
  __shared__ __align__(16) char smraw[40960];
  u16 (*bufA)[64][40]    = (u16 (*)[64][40])smraw;                 // 2*5120
  u16 (*bufB)[3][64][40] = (u16 (*)[3][64][40])(smraw + 10240);    // 2*15360

  const int tid  = threadIdx.x;
  const int lane = tid & 63;
  const int wave = tid >> 6;
  const int wr = wave >> 1, wc = wave & 1;
  const int m16 = lane & 15, kg = lane >> 4;
  const int row_s = tid >> 2, kc = (tid & 3) * 8;

  int e = tab[blockIdx.x];
  if (e == 0xFFFF) return;
  const int L = e >> 12, lb = e & 0xFFF;
  const int t = s - L;
  if (t < 0 || t >= TT) return;
  const int cur0 = s & 1, prv = cur0 ^ 1;

  if (L == 3) {
    // ---- output projection + softmax for t = s-3 ----
    u16 (*ldsA)[40]  = (u16 (*)[40])smraw;
    u16 (*ldsBo)[40] = (u16 (*)[40])(smraw + 5120);
    float (*ldsL)[67] = (float (*)[67])(smraw + 10240);
    const int r0 = lb * 64;
    const u16* A = h3b + (size_t)prv * BB * H3P;
    f32x4 acc[2][2];
    f32x4 z4 = {0.f, 0.f, 0.f, 0.f};
    for (int a = 0; a < 2; ++a) for (int b = 0; b < 2; ++b) acc[a][b] = z4;
    for (int ks = 0; ks < H3P / 32; ++ks) {
      int k0 = ks * 32;
      *(int4*)(&ldsA[row_s][kc])  = *(const int4*)(&A[(size_t)(r0 + row_s) * H3P + k0 + kc]);
      *(int4*)(&ldsBo[row_s][kc]) = *(const int4*)(&WoT[(size_t)row_s * H3P + k0 + kc]);
      __syncthreads();
      s16x8 af[2], bfr[2];
      #pragma unroll
      for (int fm = 0; fm < 2; ++fm) af[fm] = *(const s16x8*)(&ldsA[wr * 32 + fm * 16 + m16][kg * 8]);
      #pragma unroll
      for (int fn = 0; fn < 2; ++fn) bfr[fn] = *(const s16x8*)(&ldsBo[wc * 32 + fn * 16 + m16][kg * 8]);
      #pragma unroll
      for (int fm = 0; fm < 2; ++fm)
        #pragma unroll
        for (int fn = 0; fn < 2; ++fn)
          acc[fm][fn] = __builtin_amdgcn_mfma_f32_16x16x32_bf16(af[fm], bfr[fn], acc[fm][fn], 0, 0, 0);
      __syncthreads();
    }
    #pragma unroll
    for (int fn = 0; fn < 2; ++fn) {
      int c = wc * 32 + fn * 16 + m16;
      float bov = (c < CH) ? bo[c] : 0.f;
      #pragma unroll
      for (int fm = 0; fm < 2; ++fm)
        #pragma unroll
        for (int ii = 0; ii < 4; ++ii)
          ldsL[wr * 32 + fm * 16 + kg * 4 + ii][c] = acc[fm][fn][ii] + bov;
    }
    __syncthreads();
    if (tid < 64) {
      int b = r0 + tid;
      float mx = -1e30f;
      for (int c = 0; c < CH; ++c) mx = fmaxf(mx, ldsL[tid][c]);
      float sum = 0.f;
      for (int c = 0; c < CH; ++c) sum += expf(ldsL[tid][c] - mx);
      float inv = 1.f / sum;
      size_t ob = ((size_t)b * TT + t) * CH;
      for (int c = 0; c < CH; ++c) out[ob + c] = expf(ldsL[tid][c] - mx) * inv;
    }
    return;
  }

  // ---- GRU layers: merged x-seg + h-seg, double-buffered, one barrier/step ----
  int H, HP, NJ, Ks0, Ks1;
  const u16 *A0, *W0, *A1, *W1s;
  int As0, Ws0, As1, Ws1;
  const float *bi = nullptr, *bh;
  float *hfP, *hfC; u16 *hbC;
  if (L == 0) {
    H = HH1; HP = H1P; NJ = 11;
    Ks0 = 0;  A0 = A1 = h1b + (size_t)prv * BB * H1P; As0 = As1 = H1P;
    W0 = W1s = WhT1; Ws0 = Ws1 = H1P; Ks1 = 22;
    bh = gbh1;
    hfP = h1f + (size_t)prv * BB * H1P; hfC = h1f + (size_t)cur0 * BB * H1P; hbC = h1b + (size_t)cur0 * BB * H1P;
  } else if (L == 1) {
    H = HH1; HP = H1P; NJ = 11;
    Ks0 = 22; A0 = h1b + (size_t)prv * BB * H1P; As0 = H1P; W0 = WiT2; Ws0 = H1P;
    Ks1 = 22; A1 = h2b + (size_t)prv * BB * H1P; As1 = H1P; W1s = WhT2; Ws1 = H1P;
    bi = gbi2; bh = gbh2;
    hfP = h2f + (size_t)prv * BB * H1P; hfC = h2f + (size_t)cur0 * BB * H1P; hbC = h2b + (size_t)cur0 * BB * H1P;
  } else {
    H = HH3; HP = H3P; NJ = 15;
    Ks0 = 22; A0 = h2b + (size_t)prv * BB * H1P; As0 = H1P; W0 = WiT3; Ws0 = H1P;
    Ks1 = 30; A1 = h3b + (size_t)prv * BB * H3P; As1 = H3P; W1s = WhT3; Ws1 = H3P;
    bi = gbi3; bh = gbh3;
    hfP = h3f + (size_t)prv * BB * H3P; hfC = h3f + (size_t)cur0 * BB * H3P; hbC = h3b + (size_t)cur0 * BB * H3P;
  }
  const int mi = lb / NJ, ni = lb % NJ;
  const int r0 = mi * 64, j0 = ni * 64;
  const int total = Ks0 + Ks1;

  // acc groups: 0 = z (x+h summed), 1 = r (summed), 2 = xh, 3 = rh
  f32x4 acc[4][2][2];
  {
    f32x4 z4 = {0.f, 0.f, 0.f, 0.f};
    for (int g = 0; g < 4; ++g) for (int a = 0; a < 2; ++a) for (int b = 0; b < 2; ++b) acc[g][a][b] = z4;
  }

  int4 rA, rB0, rB1, rB2;
  #define GLOAD(IDX) do { \
    int i_ = (IDX); \
    int sx_ = (i_ < Ks0); \
    int ks_ = sx_ ? i_ : i_ - Ks0; \
    const u16* A_ = sx_ ? A0 : A1; \
    const u16* W_ = sx_ ? W0 : W1s; \
    int As_ = sx_ ? As0 : As1; \
    int Ws_ = sx_ ? Ws0 : Ws1; \
    const u16* ap = A_ + (size_t)(r0 + row_s) * As_ + ks_ * 32 + kc; \
    const u16* wp = W_ + (size_t)(j0 + row_s) * Ws_ + ks_ * 32 + kc; \
    rA  = *(const int4*)ap; \
    rB0 = *(const int4*)wp; \
    rB1 = *(const int4*)(wp + (size_t)H * Ws_); \
    rB2 = *(const int4*)(wp + (size_t)(2 * H) * Ws_); \
  } while (0)

  #define STLDS(BUF) do { \
    int b_ = (BUF); \
    *(int4*)(&bufA[b_][row_s][kc])    = rA; \
    *(int4*)(&bufB[b_][0][row_s][kc]) = rB0; \
    *(int4*)(&bufB[b_][1][row_s][kc]) = rB1; \
    *(int4*)(&bufB[b_][2][row_s][kc]) = rB2; \
  } while (0)

  GLOAD(0); STLDS(0); __syncthreads();
  int cur = 0;
  for (int idx = 0; idx < total; ++idx) {
    const bool sx = (idx < Ks0);
    const bool lastI = (idx == total - 1);
    if (!lastI) GLOAD(idx + 1);
    s16x8 af[2], b0[2], b1[2], b2[2];
    #pragma unroll
    for (int fm = 0; fm < 2; ++fm) af[fm] = *(const s16x8*)(&bufA[cur][wr * 32 + fm * 16 + m16][kg * 8]);
    #pragma unroll
    for (int fn = 0; fn < 2; ++fn) {
      b0[fn] = *(const s16x8*)(&bufB[cur][0][wc * 32 + fn * 16 + m16][kg * 8]);
      b1[fn] = *(const s16x8*)(&bufB[cur][1][wc * 32 + fn * 16 + m16][kg * 8]);
      b2[fn] = *(const s16x8*)(&bufB[cur][2][wc * 32 + fn * 16 + m16][kg * 8]);
    }
    if (sx) {
      #pragma unroll
      for (int fm = 0; fm < 2; ++fm)
        #pragma unroll
        for (int fn = 0; fn < 2; ++fn) {
          acc[0][fm][fn] = __builtin_amdgcn_mfma_f32_16x16x32_bf16(af[fm], b0[fn], acc[0][fm][fn], 0, 0, 0);
          acc[1][fm][fn] = __builtin_amdgcn_mfma_f32_16x16x32_bf16(af[fm], b1[fn], acc[1][fm][fn], 0, 0, 0);
          acc[2][fm][fn] = __builtin_amdgcn_mfma_f32_16x16x32_bf16(af[fm], b2[fn], acc[2][fm][fn], 0, 0, 0);
        }
    } else {
      #pragma unroll
      for (int fm = 0; fm < 2; ++fm)
        #pragma unroll
        for (int fn = 0; fn < 2; ++fn) {
          acc[0][fm][fn] = __builtin_amdgcn_mfma_f32_16x16x32_bf16(af[fm], b0[fn], acc[0][fm][fn], 0, 0, 0);
          acc[1][fm][fn] = __builtin_amdgcn_mfma_f32_16x16x32_bf16(af[fm], b1[fn], acc[1][fm][fn], 0, 0, 0);
          acc[3][fm][fn] = __builtin_amdgcn_mfma_f32_16x16x32_bf16(af[fm], b2[fn], acc[3][fm][fn], 0, 0, 0);
        }
    }
    if (!lastI) { STLDS(cur ^ 1); __syncthreads(); cur ^= 1; }
  }
  #undef GLOAD
  #undef STLDS

  // ---- gate epilogue ----
  #pragma unroll
  for (int fn = 0; fn < 2; ++fn) {
    int j = j0 + wc * 32 + fn * 16 + m16;
    if (j >= H) continue;
    float bhz = bh[j], bhr = bh[H + j], bhh = bh[2 * H + j];
    float biz = 0.f, bir = 0.f, bih = 0.f;
    if (L != 0) { biz = bi[j]; bir = bi[H + j]; bih = bi[2 * H + j]; }
    #pragma unroll
    for (int fm = 0; fm < 2; ++fm) {
      #pragma unroll
      for (int ii = 0; ii < 4; ++ii) {
        int row = r0 + wr * 32 + fm * 16 + kg * 4 + ii;
        float az  = acc[0][fm][fn][ii];
        float ar  = acc[1][fm][fn][ii];
        float axh = acc[2][fm][fn][ii];
        float arh = acc[3][fm][fn][ii];
        float pz, pr, xh_, rh_;
        if (L == 0) {
          const float* xr_ = xp1 + (size_t)row * 2112;
          pz  = xr_[j] + az + bhz;
          pr  = xr_[HH1 + j] + ar + bhr;
          xh_ = xr_[2 * HH1 + j];
          rh_ = arh + bhh;
        } else {
          pz  = az + biz + bhz;
          pr  = ar + bir + bhr;
          xh_ = axh + bih;
          rh_ = arh + bhh;
        }
        float zg = 1.f / (1.f + expf(-pz));
        float rg = 1.f / (1.f + expf(-pr));
        float hh = tanhf(xh_ + rg * rh_);
        float hp = hfP[(size_t)row * HP + j];
        float hn = zg * hp + (1.f - zg) * hh;
        hfC[(size_t)row * HP + j] = hn;
        hbC[(size_t)row * HP + j] = f2b(hn);
      }
    }
  }
}

// ---------------- host ----------------
extern "C" void kernel_launch(void* const* d_in, const int* in_sizes, int n_in,
                              void* d_out, int out_size, void* d_ws, size_t ws_size,
                              hipStream_t stream)
{
  const float* z    = (const float*)d_in[0];
  const float* W1   = (const float*)d_in[1];
  const float* b1   = (const float*)d_in[2];
  const float* gWi1 = (const float*)d_in[3];
  const float* gWh1 = (const float*)d_in[4];
  const float* gbi1 = (const float*)d_in[5];
  const float* gbh1 = (const float*)d_in[6];
  const float* gWi2 = (const float*)d_in[7];
  const float* gWh2 = (const float*)d_in[8];
  const float* gbi2 = (const float*)d_in[9];
  const float* gbh2 = (const float*)d_in[10];
  const float* gWi3 = (const float*)d_in[11];
  const float* gWh3 = (const float*)d_in[12];
  const float* gbi3 = (const float*)d_in[13];
  const float* gbh3 = (const float*)d_in[14];
  const float* Wo   = (const float*)d_in[15];
  const float* bo   = (const float*)d_in[16];

  char* ws = (char*)d_ws;
  float* x_f  = (float*)(ws + O_X);
  float* xp1  = (float*)(ws + O_XP1);
  float* h1f  = (float*)(ws + O_H1F);
  float* h2f  = (float*)(ws + O_H2F);
  float* h3f  = (float*)(ws + O_H3F);
  u16*   h1b  = (u16*)(ws + O_H1B);
  u16*   h2b  = (u16*)(ws + O_H2B);
  u16*   h3b  = (u16*)(ws + O_H3B);
  u16*   WhT1 = (u16*)(ws + O_WHT1);
  u16*   WiT2 = (u16*)(ws + O_WIT2);
  u16*   WhT2 = (u16*)(ws + O_WHT2);
  u16*   WiT3 = (u16*)(ws + O_WIT3);
  u16*   WhT3 = (u16*)(ws + O_WHT3);
  u16*   WoT  = (u16*)(ws + O_WOT);
  u16*   tab  = (u16*)(ws + O_TAB);

  hipMemsetAsync(ws + O_H1F, 0, ZERO_BYTES, stream);

  k_maketab<<<1, 64, 0, stream>>>(tab);
  k_selu<<<(BB * LAT + 255) / 256, 256, 0, stream>>>(z, W1, b1, x_f);
  k_xp1<<<9 * 64, 256, 0, stream>>>(x_f, gWi1, gbi1, xp1);

  k_transpose<<<11 * 33, 256, 0, stream>>>(gWh1, WhT1, 701, 2103, 704, 2112);
  k_transpose<<<11 * 33, 256, 0, stream>>>(gWi2, WiT2, 701, 2103, 704, 2112);
  k_transpose<<<11 * 33, 256, 0, stream>>>(gWh2, WhT2, 701, 2103, 704, 2112);
  k_transpose<<<11 * 44, 256, 0, stream>>>(gWi3, WiT3, 701, 2703, 704, 2816);
  k_transpose<<<15 * 44, 256, 0, stream>>>(gWh3, WhT3, 901, 2703, 960, 2816);
  k_transpose<<<15 * 1, 256, 0, stream>>>(Wo, WoT, 901, 35, 960, 64);

  for (int s = 0; s < TT + 3; ++s)
    k_wave<<<GRID, 256, 0, stream>>>(s, tab, WhT1, WiT2, WhT2, WiT3, WhT3, WoT, xp1,
                                     gbh1, gbi2, gbh2, gbi3, gbh3, bo,
                                     h1f, h1b, h2f, h2b, h3f, h3b, (float*)d_out);
}